// Round 2
// baseline (1868.558 us; speedup 1.0000x reference)
//
#include <hip/hip_runtime.h>
#include <stdint.h>

// ModeloNeuralVasicek — two-phase mean-recursion.
// Round 18 (resubmit; R1 bench was an infra "container failed twice" error).
// Tangent-pipelined scan: the 1470cy/step serial chain
// (layer1 -> LDS rt -> MFMA -> gelu2 -> DPP -> msum exchange -> softplus)
// is replaced by a depth-2 pipeline: step s's MLP is evaluated at anchor
// a_s = r_{s-2} (known 2 iterations early) together with its d/dr tangent
// (forward-mode AD). The tangent rides MFMA A-rows 1 mod 4 — previously
// broadcast-wasted — so layer-2 costs the SAME 16 MFMAs + 4 ds_read_b128.
// Serial update becomes mu = mu_a + dmu*(r_s - a_s) (ditto si pre-softplus).
// |r_s - a_s| <~ 2e-2 -> h1 interp error ~1e-8, invisible vs f16 noise.
// Iteration is now issue-bound (~420cy), not latency-bound.

#define NSTEPS 2520
#define NB 64
#define NT 256
#define NQ 256
#define NMAT 7

typedef uint32_t u32x4 __attribute__((ext_vector_type(4)));
typedef float f32x4 __attribute__((ext_vector_type(4)));

__device__ __forceinline__ uint32_t rotl32(uint32_t v, int n) {
  return (v << n) | (v >> (32 - n));
}

// Threefry-2x32, 20 rounds — matches jax._src.prng.threefry2x32 exactly.
__device__ __forceinline__ void tf2x32(uint32_t k0, uint32_t k1,
                                       uint32_t x0, uint32_t x1,
                                       uint32_t& o0, uint32_t& o1) {
  const uint32_t k2 = k0 ^ k1 ^ 0x1BD11BDAu;
  x0 += k0; x1 += k1;
#define R4(a,b,c,d) \
  x0 += x1; x1 = rotl32(x1,(a)); x1 ^= x0; \
  x0 += x1; x1 = rotl32(x1,(b)); x1 ^= x0; \
  x0 += x1; x1 = rotl32(x1,(c)); x1 ^= x0; \
  x0 += x1; x1 = rotl32(x1,(d)); x1 ^= x0;
  R4(13,15,26,6)  x0 += k1; x1 += k2 + 1u;
  R4(17,29,16,24) x0 += k2; x1 += k0 + 2u;
  R4(13,15,26,6)  x0 += k0; x1 += k1 + 3u;
  R4(17,29,16,24) x0 += k1; x1 += k2 + 4u;
  R4(13,15,26,6)  x0 += k2; x1 += k0 + 5u;
#undef R4
  o0 = x0; o1 = x1;
}

// fast reciprocal: v_rcp + one Newton step (~1e-7 rel; replaces full f32 div)
__device__ __forceinline__ float fast_rcp(float q) {
  float r = __builtin_amdgcn_rcpf(q);
  r = __builtin_fmaf(r, __builtin_fmaf(-q, r, 1.0f), r);
  return r;
}

// Eigen/XLA generic_fast_tanh_float (preamble only; keep full precision).
__device__ __forceinline__ float eigen_tanh(float a_x) {
  float x = fminf(fmaxf(a_x, -7.90531110763549805f), 7.90531110763549805f);
  float x2 = x * x;
  float p = __builtin_fmaf(x2, -2.76076847742355e-16f, 2.00018790482477e-13f);
  p = __builtin_fmaf(x2, p, -8.60467152213735e-11f);
  p = __builtin_fmaf(x2, p, 5.12229709037114e-08f);
  p = __builtin_fmaf(x2, p, 1.48572235717979e-05f);
  p = __builtin_fmaf(x2, p, 6.37261928875436e-04f);
  p = __builtin_fmaf(x2, p, 4.89352455891786e-03f);
  p = x * p;
  float q = __builtin_fmaf(x2, 1.19825839466702e-06f, 1.18534705686654e-04f);
  q = __builtin_fmaf(x2, q, 2.26843463243900e-03f);
  q = __builtin_fmaf(x2, q, 4.89352518554385e-03f);
  float rr = p / q;
  return (fabsf(a_x) < 0.0004f) ? a_x : rr;
}

// Eigen/XLA erf polynomial with rcp-division (scan loop hot path).
__device__ __forceinline__ float eigen_erf_fast(float a_x) {
  float x = fminf(fmaxf(a_x, -4.0f), 4.0f);
  float x2 = x * x;
  float p = __builtin_fmaf(x2, -2.72614225801306e-10f, 2.77068142495902e-08f);
  p = __builtin_fmaf(x2, p, -2.10102402082508e-06f);
  p = __builtin_fmaf(x2, p, -5.69250639462346e-05f);
  p = __builtin_fmaf(x2, p, -7.34990630326855e-04f);
  p = __builtin_fmaf(x2, p, -2.95459980854025e-03f);
  p = __builtin_fmaf(x2, p, -1.60960333262415e-02f);
  p = x * p;
  float q = __builtin_fmaf(x2, -1.45660718464996e-05f, -2.13374055278905e-04f);
  q = __builtin_fmaf(x2, q, -1.68282697438203e-03f);
  q = __builtin_fmaf(x2, q, -7.37332916720468e-03f);
  q = __builtin_fmaf(x2, q, -1.42647390514189e-02f);
  return p * fast_rcp(q);
}

// fast softplus: __expf/__logf (v_exp/v_log based), abs err ~1e-6
__device__ __forceinline__ float softplus_fast(float x) {
  float e = __expf(-fabsf(x));
  return fmaxf(x, 0.0f) + __logf(1.0f + e);
}

// XLA chlo.erf_inv f32 (Giles polynomial) — phase 1 only, keep exact.
__device__ __forceinline__ float erfinv_xla(float x) {
  float w = -logf((1.0f - x) * (1.0f + x));
  float p;
  if (w < 5.0f) {
    w = w - 2.5f;
    p = 2.81022636e-08f;
    p = __builtin_fmaf(p, w, 3.43273939e-07f);
    p = __builtin_fmaf(p, w, -3.5233877e-06f);
    p = __builtin_fmaf(p, w, -4.39150654e-06f);
    p = __builtin_fmaf(p, w, 0.00021858087f);
    p = __builtin_fmaf(p, w, -0.00125372503f);
    p = __builtin_fmaf(p, w, -0.00417768164f);
    p = __builtin_fmaf(p, w, 0.246640727f);
    p = __builtin_fmaf(p, w, 1.50140941f);
  } else {
    w = sqrtf(w) - 3.0f;
    p = -0.000200214257f;
    p = __builtin_fmaf(p, w, 0.000100950558f);
    p = __builtin_fmaf(p, w, 0.00134934322f);
    p = __builtin_fmaf(p, w, -0.00367342844f);
    p = __builtin_fmaf(p, w, 0.00573950773f);
    p = __builtin_fmaf(p, w, -0.0076224613f);
    p = __builtin_fmaf(p, w, 0.00943887047f);
    p = __builtin_fmaf(p, w, 1.00167406f);
    p = __builtin_fmaf(p, w, 2.83297682f);
  }
  return p * x;
}

__device__ __forceinline__ float bits_to_normal(uint32_t bits) {
  const float MINVAL = -0.999999940395355224609375f;
  uint32_t fb = (bits >> 9) | 0x3F800000u;
  float f01 = __uint_as_float(fb) - 1.0f;
  float u = f01 * 2.0f + MINVAL;
  u = fmaxf(u, MINVAL);
  return 1.41421356237309515f * erfinv_xla(u);
}

__device__ __forceinline__ uint16_t f32_to_f16bits(float x) {
  _Float16 hv = (_Float16)x;  // RNE
  return __builtin_bit_cast(uint16_t, hv);
}

__device__ __forceinline__ uint32_t pack_f16x2(float lo, float hi) {
  return (uint32_t)f32_to_f16bits(lo) | ((uint32_t)f32_to_f16bits(hi) << 16);
}

// DPP add: v += dpp_move(v) — VALU pipe, replaces DS-pipe shuffles.
// CTRL: 0x111..0x118 = row_shr 1..8; 0x142 = row_bcast15; 0x143 = row_bcast31.
template <int CTRL, int RMASK>
__device__ __forceinline__ float dpp_add(float v) {
  int x = __builtin_amdgcn_update_dpp(0, __float_as_int(v), CTRL, RMASK, 0xf, true);
  return v + __int_as_float(x);
}

// 64-lane sum lands in lane 63 (R15/R17-validated chain).
__device__ __forceinline__ float dpp_reduce63(float p) {
  p = dpp_add<0x111, 0xf>(p);   // row_shr:1
  p = dpp_add<0x112, 0xf>(p);   // row_shr:2
  p = dpp_add<0x114, 0xf>(p);   // row_shr:4
  p = dpp_add<0x118, 0xf>(p);   // row_shr:8
  p = dpp_add<0x142, 0xa>(p);   // row_bcast:15 -> rows 1,3
  p = dpp_add<0x143, 0xc>(p);   // row_bcast:31 -> rows 2,3
  return p;
}

#define DTF  0.00396825396825396826f
#define SQDT 0.06299407883487120442f
#define TSTEP (1.0f / 2519.0f)
// tangents are scaled by 64 for f16 headroom; update folds the 1/64 back in
#define TSC      64.0f
#define TSC_INV  0.015625f
#define INV_SQRT2 0.7071067811865475f
#define PHI_C     0.3989422804014327f

// ---------------- Phase 1: mean_dW[b][s] — fully parallel ----------------
__global__ __launch_bounds__(256)
void vasicek_phase1_meandw(float* __restrict__ ws) {
  const int tid = threadIdx.x;
  const int lane = tid & 63;
  const int wv = tid >> 6;
  const int wid = blockIdx.x * 4 + wv;          // 0 .. 64*2520-1
  const int b = wid / NSTEPS;
  const int s = wid - b * NSTEPS;

  uint32_t kA, kB;
  tf2x32(0u, 1u, 0u, (uint32_t)s, kA, kB);      // split(key(1))[s]

  float sum = 0.f;
#pragma unroll
  for (int i = 0; i < 4; ++i) {
    uint32_t cnt = (uint32_t)(b * NQ + lane + i * 64);
    uint32_t q0, q1;
    tf2x32(kA, kB, 0u, cnt, q0, q1);
    float dw = bits_to_normal(q0 ^ q1) * SQDT;
    sum += dw;
  }
  sum += __shfl_xor(sum, 32, 64); sum += __shfl_xor(sum, 16, 64);
  sum += __shfl_xor(sum, 8, 64);  sum += __shfl_xor(sum, 4, 64);
  sum += __shfl_xor(sum, 2, 64);  sum += __shfl_xor(sum, 1, 64);
  if (lane == 0) ws[b * NSTEPS + s] = sum * (1.0f / 256.0f);
}

// ---- B-fragment machinery, k-PERMUTED to match the packed h1 layout:
// h1 dword l = (h1[l], h1[l+64]) => B dword d of tile T (lane q,n) must hold
// W2 rows (16T+4q+d, 64+16T+4q+d) at column 16*(4*half+C)+n, f16x2 packed.
#define BDECL(T, C) u32x4 b_##T##_##C;
#define BINIT(T, C) { \
  const int col_ = 16 * (4 * half + (C)) + n; \
  const int r0_ = 16 * (T) + 4 * q; \
  b_##T##_##C = (u32x4){ \
    pack_f16x2(W2src[(r0_ + 0) * 128 + col_], W2src[(r0_ + 64) * 128 + col_]), \
    pack_f16x2(W2src[(r0_ + 1) * 128 + col_], W2src[(r0_ + 65) * 128 + col_]), \
    pack_f16x2(W2src[(r0_ + 2) * 128 + col_], W2src[(r0_ + 66) * 128 + col_]), \
    pack_f16x2(W2src[(r0_ + 3) * 128 + col_], W2src[(r0_ + 67) * 128 + col_])}; \
  asm volatile("" : "+a"(b_##T##_##C)); /* pin in AGPR quad */ \
}
#define MFMA1(ACC, AF, BF) \
  asm("v_mfma_f32_16x16x32_f16 %0, %1, %2, %0" : "+v"(ACC) : "v"(AF), "a"(BF));
#define COLCHAIN(ACC, C) \
  MFMA1(ACC, af0, b_0_##C) MFMA1(ACC, af1, b_1_##C) \
  MFMA1(ACC, af2, b_2_##C) MFMA1(ACC, af3, b_3_##C)

// layer-1 for step with time TV, anchor RANCH; writes value+tangent h1
// buffers at SLOT. A-rows n%4==0 read h1p (value), n%4==1 read h1d (tangent).
#define STAGE3(TV, SLOT, RANCH) { \
  float prea = __builtin_fmaf((TV), w11a, __builtin_fmaf((RANCH), w10a, c1a)); \
  float preb = __builtin_fmaf((TV), w11b, __builtin_fmaf((RANCH), w10b, c1b)); \
  float ea = eigen_erf_fast(prea * INV_SQRT2); \
  float ca = (ea + 1.0f) * 0.5f; \
  float va = prea * ca; \
  float eb = eigen_erf_fast(preb * INV_SQRT2); \
  float cb = (eb + 1.0f) * 0.5f; \
  float vb = preb * cb; \
  float pha = PHI_C * __expf(-0.5f * prea * prea); \
  float phb = PHI_C * __expf(-0.5f * preb * preb); \
  float da = __builtin_fmaf(prea, pha, ca) * w10aS; /* gelu'(pre)*w10*64 */ \
  float db = __builtin_fmaf(preb, phb, cb) * w10bS; \
  h1p[SLOT][wv][lane] = pack_f16x2(va, vb); \
  h1d[SLOT][wv][lane] = pack_f16x2(da, db); \
}

// MFMA + gelu2(value & tangent) + DPP reduce + msum[SLOT] write.
// Uses af0..af3 from enclosing scope. acc[0]=h2 value row, acc[1]=tangent row.
#define STAGE1C(SLOT) { \
  f32x4 a0v = {0,0,0,0}, a1v = {0,0,0,0}, a2v = {0,0,0,0}, a3v = {0,0,0,0}; \
  COLCHAIN(a0v, 0) COLCHAIN(a1v, 1) COLCHAIN(a2v, 2) COLCHAIN(a3v, 3) \
  asm volatile("s_nop 7\n\ts_nop 7" \
               : "+v"(a0v), "+v"(a1v), "+v"(a2v), "+v"(a3v)); \
  float yv = (q == 0 ? a0v[0] : q == 1 ? a1v[0] : q == 2 ? a2v[0] : a3v[0]) + b2E; \
  float yt = (q == 0 ? a0v[1] : q == 1 ? a1v[1] : q == 2 ? a2v[1] : a3v[1]); \
  float ev = eigen_erf_fast(yv * INV_SQRT2); \
  float cv = (ev + 1.0f) * 0.5f; \
  float pv = yv * cv * w3E; \
  float phv = PHI_C * __expf(-0.5f * yv * yv); \
  float pt = __builtin_fmaf(yv, phv, cv) * yt * w3E; \
  pv = dpp_reduce63(pv); \
  pt = dpp_reduce63(pt); \
  if (lane == 63) { msum[SLOT][wv][0] = pv; msum[SLOT][wv][1] = pt; } \
}

// ---------------- Phase 2: scan, 64 blocks x 256 ---------------------------
__global__
__attribute__((amdgpu_flat_work_group_size(256, 256)))
__attribute__((amdgpu_waves_per_eu(1, 1)))
void vasicek_phase2_scan(
    const float* __restrict__ X, const float* __restrict__ r_ult,
    const float* __restrict__ mats,
    const float* __restrict__ Wp, const float* __restrict__ bp,
    const float* __restrict__ ln_g, const float* __restrict__ ln_b,
    const float* __restrict__ muW1, const float* __restrict__ mub1,
    const float* __restrict__ muW2, const float* __restrict__ mub2,
    const float* __restrict__ muW3, const float* __restrict__ mub3,
    const float* __restrict__ siW1, const float* __restrict__ sib1,
    const float* __restrict__ siW2, const float* __restrict__ sib2,
    const float* __restrict__ siW3, const float* __restrict__ sib3,
    const float* __restrict__ ws, float* __restrict__ out) {
  __shared__ __align__(16) uint32_t h1p[2][4][64];  // [slot][wave] packed h1 values
  __shared__ __align__(16) uint32_t h1d[2][4][64];  // [slot][wave] packed h1 tangents*64
  __shared__ float meanw[NSTEPS];
  __shared__ float part[256];
  __shared__ float mbuf[64];
  __shared__ float ctx_lds[192];
  __shared__ __align__(16) float msum[2][4][2];     // [slot][wave][{val,tan}]

  const int t = threadIdx.x;
  const int b = blockIdx.x;
  const int lane = t & 63;
  const int wv = t >> 6;

  for (int i = t; i < NSTEPS; i += 256) meanw[i] = ws[b * NSTEPS + i];

  // ---- context aggregator (all 256 threads, one T-row each) ----
  float h[64];
  {
    float x0 = X[(b * NT + t) * 2 + 0];
    float x1 = X[(b * NT + t) * 2 + 1];
    float s = 0.f;
#pragma unroll
    for (int c = 0; c < 64; ++c) {
      float pre = __builtin_fmaf(x1, Wp[64 + c], x0 * Wp[c]) + bp[c];
      h[c] = eigen_tanh(pre);
      s += h[c];
    }
    float m = s * 0.015625f;
    float vs = 0.f;
#pragma unroll
    for (int c = 0; c < 64; ++c) { float d = h[c] - m; vs = __builtin_fmaf(d, d, vs); }
    float den = sqrtf(vs * 0.015625f + 1e-5f);
#pragma unroll
    for (int c = 0; c < 64; ++c)
      h[c] = ((h[c] - m) / den) * ln_g[c] + ln_b[c];
  }
#pragma unroll
  for (int c = 0; c < 64; ++c) {
    float v = h[c];
    v += __shfl_xor(v, 32, 64); v += __shfl_xor(v, 16, 64);
    v += __shfl_xor(v, 8, 64);  v += __shfl_xor(v, 4, 64);
    v += __shfl_xor(v, 2, 64);  v += __shfl_xor(v, 1, 64);
    if (lane == 0) part[wv * 64 + c] = v;
  }
  __syncthreads();
  if (t < 64) {
    float m = ((part[t] + part[64 + t]) + (part[128 + t] + part[192 + t])) * (1.0f / 256.0f);
    mbuf[t] = m;
    ctx_lds[t] = m;
  }
  __syncthreads();
#pragma unroll
  for (int c = 0; c < 64; ++c) {
    float d = h[c] - mbuf[c];
    float v = d * d;
    v += __shfl_xor(v, 32, 64); v += __shfl_xor(v, 16, 64);
    v += __shfl_xor(v, 8, 64);  v += __shfl_xor(v, 4, 64);
    v += __shfl_xor(v, 2, 64);  v += __shfl_xor(v, 1, 64);
    if (lane == 0) part[wv * 64 + c] = v;
  }
  if (t == 255) {
#pragma unroll
    for (int c = 0; c < 64; ++c) ctx_lds[128 + c] = h[c];
  }
  __syncthreads();
  if (t < 64) {
    float vs = (part[t] + part[64 + t]) + (part[128 + t] + part[192 + t]);
    ctx_lds[64 + t] = sqrtf(vs / 255.0f);
  }
  __syncthreads();

  // ---- per-wave roles: mlp = wv>>1 (0=mu,1=si), half = wv&1 ----
  const int mlp = wv >> 1;
  const int half = wv & 1;
  const int j0 = lane, j1 = lane + 64;        // layer-1 ownership (full h1)
  const int jE = 64 * half + lane;            // epilogue ownership (h2 half)
  const float* W1 = mlp == 0 ? muW1 : siW1;
  const float* W2src = mlp == 0 ? muW2 : siW2;
  float c1a = (mlp == 0 ? mub1 : sib1)[j0];
  float c1b = (mlp == 0 ? mub1 : sib1)[j1];
  for (int c = 0; c < 192; ++c) {
    const float cx = ctx_lds[c];
    c1a = __builtin_fmaf(cx, W1[(2 + c) * 128 + j0], c1a);
    c1b = __builtin_fmaf(cx, W1[(2 + c) * 128 + j1], c1b);
  }
  const float w10a = W1[j0], w11a = W1[128 + j0];
  const float w10b = W1[j1], w11b = W1[128 + j1];
  const float w10aS = w10a * TSC, w10bS = w10b * TSC;
  const float b2E = (mlp == 0 ? mub2 : sib2)[jE];
  const float w3E = (mlp == 0 ? muW3 : siW3)[jE];
  const float b3mu = mub3[0], b3si = sib3[0];

  const int q = lane >> 4, n = lane & 15;

  // this wave's 4 col-tiles of its W2 -> 16 AGPR quads (one-time; pinned)
  BDECL(0,0) BDECL(0,1) BDECL(0,2) BDECL(0,3)
  BDECL(1,0) BDECL(1,1) BDECL(1,2) BDECL(1,3)
  BDECL(2,0) BDECL(2,1) BDECL(2,2) BDECL(2,3)
  BDECL(3,0) BDECL(3,1) BDECL(3,2) BDECL(3,3)
  BINIT(0,0) BINIT(0,1) BINIT(0,2) BINIT(0,3)
  BINIT(1,0) BINIT(1,1) BINIT(1,2) BINIT(1,3)
  BINIT(2,0) BINIT(2,1) BINIT(2,2) BINIT(2,3)
  BINIT(3,0) BINIT(3,1) BINIT(3,2) BINIT(3,3)

  // A-row = lane&15; rows n%4==1 carry the tangent buffer, others the value.
  const bool tsel = (lane & 3) == 1;
  const u32x4* hqP0 = tsel ? (const u32x4*)&h1d[0][wv][0]
                           : (const u32x4*)&h1p[0][wv][0];
  const u32x4* hqP1 = tsel ? (const u32x4*)&h1d[1][wv][0]
                           : (const u32x4*)&h1p[1][wv][0];

  float r = r_ult[b];
  float area = 0.f;
  float a_cur = r;   // anchor used for step i   (r_{i-2}; steps 0,1 -> r0)
  float a_nxt = r;   // anchor used for step i+1

  // ---- pipeline prologue ----
  STAGE3(0.0f, 0, r)        // layer-1 for step 0 (anchor r0) -> slot 0
  STAGE3(TSTEP, 1, r)       // layer-1 for step 1 (anchor r0) -> slot 1
  {
    u32x4 af0 = hqP0[q], af1 = hqP0[4 + q], af2 = hqP0[8 + q], af3 = hqP0[12 + q];
    STAGE1C(0)              // partials for step 0 -> msum[0]
  }
  __syncthreads();

#pragma unroll 1
  for (int i = 0; i < NSTEPS; ++i) {
    const int par0 = i & 1;        // msum slot for step i; h1 slot for step i+2
    const int par1 = par0 ^ 1;     // h1 + msum slot for step i+1

    // issue long-latency LDS reads first (update consumes them ~200cy later)
    const float4 m0 = *(const float4*)&msum[par0][0][0];  // (muVal0,muTan0,muVal1,muTan1)
    const float4 m1 = *(const float4*)&msum[par0][2][0];  // (siVal0,siTan0,siVal1,siTan1)
    const float mw = meanw[i];
    const u32x4* hq = par1 ? hqP1 : hqP0;
    u32x4 af0 = hq[q], af1 = hq[4 + q], af2 = hq[8 + q], af3 = hq[12 + q];

    // layer-1 for step i+2 at anchor r_i (independent of this step's update)
    const float rA = r;
    STAGE3(TSTEP * (float)(i + 2), par0, rA)

    // layer-2/3 (value+tangent) for step i+1 -> msum[par1]
    STAGE1C(par1)

    // serial update for step i: linear correction around anchor a_cur
    float mu_a = (m0.x + m0.z) + b3mu;
    float dmu  = m0.y + m0.w;
    float z_a  = (m1.x + m1.z) + b3si;
    float dzt  = m1.y + m1.w;
    float dru = (r - a_cur) * TSC_INV;           // (r_i - a_i)/64
    float mu = __builtin_fmaf(dmu, dru, mu_a);
    float zz = __builtin_fmaf(dzt, dru, z_a);
    float si = softplus_fast(zz) + 1e-5f;
    r = __fadd_rn(__fadd_rn(r, __fmul_rn(mu, DTF)), __fmul_rn(si, mw));
    area = __fadd_rn(area, __fmul_rn(r, DTF));
    a_cur = a_nxt;
    a_nxt = rA;

    __syncthreads();  // publish msum[par1] for next iteration (the ONLY barrier)
  }

  if (t < NMAT) {
    float mx = mats[0];
#pragma unroll
    for (int i = 1; i < NMAT; ++i) mx = fmaxf(mx, mats[i]);
    const float mm = mats[t];
    const float frac = mm / (mx + 1e-12f);
    out[b * NMAT + t] = (area * frac) / (mm + 1e-12f);
  }
}

extern "C" void kernel_launch(void* const* d_in, const int* in_sizes, int n_in,
                              void* d_out, int out_size, void* d_ws, size_t ws_size,
                              hipStream_t stream) {
  (void)in_sizes; (void)n_in; (void)ws_size; (void)out_size;
  const float* X      = (const float*)d_in[0];
  const float* r_ult  = (const float*)d_in[1];
  const float* mats   = (const float*)d_in[2];
  const float* Wp     = (const float*)d_in[3];
  const float* bp     = (const float*)d_in[4];
  const float* ln_g   = (const float*)d_in[5];
  const float* ln_b   = (const float*)d_in[6];
  const float* muW1   = (const float*)d_in[7];
  const float* mub1   = (const float*)d_in[8];
  const float* muW2   = (const float*)d_in[9];
  const float* mub2   = (const float*)d_in[10];
  const float* muW3   = (const float*)d_in[11];
  const float* mub3   = (const float*)d_in[12];
  const float* siW1   = (const float*)d_in[13];
  const float* sib1   = (const float*)d_in[14];
  const float* siW2   = (const float*)d_in[15];
  const float* sib2   = (const float*)d_in[16];
  const float* siW3   = (const float*)d_in[17];
  const float* sib3   = (const float*)d_in[18];
  float* ws = (float*)d_ws;   // 64*2520*4 = 645,120 bytes

  hipLaunchKernelGGL(vasicek_phase1_meandw,
                     dim3(NB * NSTEPS / 4), dim3(256), 0, stream, ws);
  hipLaunchKernelGGL(vasicek_phase2_scan,
                     dim3(NB), dim3(256), 0, stream,
                     X, r_ult, mats, Wp, bp, ln_g, ln_b,
                     muW1, mub1, muW2, mub2, muW3, mub3,
                     siW1, sib1, siW2, sib2, siW3, sib3,
                     ws, (float*)d_out);
}

// Round 3
// 1611.939 us; speedup vs baseline: 1.1592x; 1.1592x over previous
//
#include <hip/hip_runtime.h>
#include <stdint.h>

// ModeloNeuralVasicek — two-phase mean-recursion.
// Round 19: R18 tangent pipeline kept (passed, absmax 0.0078125) but it was
// SLOWER (1695 vs 1542us): same-wave serialization + 1.03e7 LDS bank
// conflicts (h1d was +2048B == 0 mod 128 from h1p). Changes:
// (1) value/tangent in ONE buffer, tangent at +320B (== 64 mod 128):
//     conflict-free b128 A-frag reads (value lanes banks 0-15, tangent 16-31).
// (2) cross-wave h1 split: the 2 waves of an MLP each compute only their 64
//     h1 elements (ds_write_b16 halves of the shared packed dwords) — h1
//     already crosses the barrier, so sharing is free. STAGE3 halves.
// (3) 2-step unroll: one barrier per 2 steps, 32 MFMAs as 8 independent
//     4-chains (dep dist 8), 4 DPP reduces interleaved. Anchor distance
//     grows to 5-6 steps; tangent correction keeps error ~1e-6 << f16 noise.

#define NSTEPS 2520
#define NB 64
#define NT 256
#define NQ 256
#define NMAT 7

typedef uint32_t u32x4 __attribute__((ext_vector_type(4)));
typedef float f32x4 __attribute__((ext_vector_type(4)));

__device__ __forceinline__ uint32_t rotl32(uint32_t v, int n) {
  return (v << n) | (v >> (32 - n));
}

// Threefry-2x32, 20 rounds — matches jax._src.prng.threefry2x32 exactly.
__device__ __forceinline__ void tf2x32(uint32_t k0, uint32_t k1,
                                       uint32_t x0, uint32_t x1,
                                       uint32_t& o0, uint32_t& o1) {
  const uint32_t k2 = k0 ^ k1 ^ 0x1BD11BDAu;
  x0 += k0; x1 += k1;
#define R4(a,b,c,d) \
  x0 += x1; x1 = rotl32(x1,(a)); x1 ^= x0; \
  x0 += x1; x1 = rotl32(x1,(b)); x1 ^= x0; \
  x0 += x1; x1 = rotl32(x1,(c)); x1 ^= x0; \
  x0 += x1; x1 = rotl32(x1,(d)); x1 ^= x0;
  R4(13,15,26,6)  x0 += k1; x1 += k2 + 1u;
  R4(17,29,16,24) x0 += k2; x1 += k0 + 2u;
  R4(13,15,26,6)  x0 += k0; x1 += k1 + 3u;
  R4(17,29,16,24) x0 += k1; x1 += k2 + 4u;
  R4(13,15,26,6)  x0 += k2; x1 += k0 + 5u;
#undef R4
  o0 = x0; o1 = x1;
}

// fast reciprocal: v_rcp + one Newton step (~1e-7 rel; replaces full f32 div)
__device__ __forceinline__ float fast_rcp(float q) {
  float r = __builtin_amdgcn_rcpf(q);
  r = __builtin_fmaf(r, __builtin_fmaf(-q, r, 1.0f), r);
  return r;
}

// Eigen/XLA generic_fast_tanh_float (preamble only; keep full precision).
__device__ __forceinline__ float eigen_tanh(float a_x) {
  float x = fminf(fmaxf(a_x, -7.90531110763549805f), 7.90531110763549805f);
  float x2 = x * x;
  float p = __builtin_fmaf(x2, -2.76076847742355e-16f, 2.00018790482477e-13f);
  p = __builtin_fmaf(x2, p, -8.60467152213735e-11f);
  p = __builtin_fmaf(x2, p, 5.12229709037114e-08f);
  p = __builtin_fmaf(x2, p, 1.48572235717979e-05f);
  p = __builtin_fmaf(x2, p, 6.37261928875436e-04f);
  p = __builtin_fmaf(x2, p, 4.89352455891786e-03f);
  p = x * p;
  float q = __builtin_fmaf(x2, 1.19825839466702e-06f, 1.18534705686654e-04f);
  q = __builtin_fmaf(x2, q, 2.26843463243900e-03f);
  q = __builtin_fmaf(x2, q, 4.89352518554385e-03f);
  float rr = p / q;
  return (fabsf(a_x) < 0.0004f) ? a_x : rr;
}

// Eigen/XLA erf polynomial with rcp-division (scan loop hot path).
__device__ __forceinline__ float eigen_erf_fast(float a_x) {
  float x = fminf(fmaxf(a_x, -4.0f), 4.0f);
  float x2 = x * x;
  float p = __builtin_fmaf(x2, -2.72614225801306e-10f, 2.77068142495902e-08f);
  p = __builtin_fmaf(x2, p, -2.10102402082508e-06f);
  p = __builtin_fmaf(x2, p, -5.69250639462346e-05f);
  p = __builtin_fmaf(x2, p, -7.34990630326855e-04f);
  p = __builtin_fmaf(x2, p, -2.95459980854025e-03f);
  p = __builtin_fmaf(x2, p, -1.60960333262415e-02f);
  p = x * p;
  float q = __builtin_fmaf(x2, -1.45660718464996e-05f, -2.13374055278905e-04f);
  q = __builtin_fmaf(x2, q, -1.68282697438203e-03f);
  q = __builtin_fmaf(x2, q, -7.37332916720468e-03f);
  q = __builtin_fmaf(x2, q, -1.42647390514189e-02f);
  return p * fast_rcp(q);
}

// fast softplus: __expf/__logf (v_exp/v_log based), abs err ~1e-6
__device__ __forceinline__ float softplus_fast(float x) {
  float e = __expf(-fabsf(x));
  return fmaxf(x, 0.0f) + __logf(1.0f + e);
}

// XLA chlo.erf_inv f32 (Giles polynomial) — phase 1 only, keep exact.
__device__ __forceinline__ float erfinv_xla(float x) {
  float w = -logf((1.0f - x) * (1.0f + x));
  float p;
  if (w < 5.0f) {
    w = w - 2.5f;
    p = 2.81022636e-08f;
    p = __builtin_fmaf(p, w, 3.43273939e-07f);
    p = __builtin_fmaf(p, w, -3.5233877e-06f);
    p = __builtin_fmaf(p, w, -4.39150654e-06f);
    p = __builtin_fmaf(p, w, 0.00021858087f);
    p = __builtin_fmaf(p, w, -0.00125372503f);
    p = __builtin_fmaf(p, w, -0.00417768164f);
    p = __builtin_fmaf(p, w, 0.246640727f);
    p = __builtin_fmaf(p, w, 1.50140941f);
  } else {
    w = sqrtf(w) - 3.0f;
    p = -0.000200214257f;
    p = __builtin_fmaf(p, w, 0.000100950558f);
    p = __builtin_fmaf(p, w, 0.00134934322f);
    p = __builtin_fmaf(p, w, -0.00367342844f);
    p = __builtin_fmaf(p, w, 0.00573950773f);
    p = __builtin_fmaf(p, w, -0.0076224613f);
    p = __builtin_fmaf(p, w, 0.00943887047f);
    p = __builtin_fmaf(p, w, 1.00167406f);
    p = __builtin_fmaf(p, w, 2.83297682f);
  }
  return p * x;
}

__device__ __forceinline__ float bits_to_normal(uint32_t bits) {
  const float MINVAL = -0.999999940395355224609375f;
  uint32_t fb = (bits >> 9) | 0x3F800000u;
  float f01 = __uint_as_float(fb) - 1.0f;
  float u = f01 * 2.0f + MINVAL;
  u = fmaxf(u, MINVAL);
  return 1.41421356237309515f * erfinv_xla(u);
}

__device__ __forceinline__ uint16_t f32_to_f16bits(float x) {
  _Float16 hv = (_Float16)x;  // RNE
  return __builtin_bit_cast(uint16_t, hv);
}

__device__ __forceinline__ uint32_t pack_f16x2(float lo, float hi) {
  return (uint32_t)f32_to_f16bits(lo) | ((uint32_t)f32_to_f16bits(hi) << 16);
}

// DPP add: v += dpp_move(v) — VALU pipe, replaces DS-pipe shuffles.
// CTRL: 0x111..0x118 = row_shr 1..8; 0x142 = row_bcast15; 0x143 = row_bcast31.
template <int CTRL, int RMASK>
__device__ __forceinline__ float dpp_add(float v) {
  int x = __builtin_amdgcn_update_dpp(0, __float_as_int(v), CTRL, RMASK, 0xf, true);
  return v + __int_as_float(x);
}

#define DTF  0.00396825396825396826f
#define SQDT 0.06299407883487120442f
#define TSTEP (1.0f / 2519.0f)
// tangents are scaled by 64 for f16 headroom; update folds the 1/64 back in
#define TSC      64.0f
#define TSC_INV  0.015625f
#define INV_SQRT2 0.7071067811865475f
#define PHI_C     0.3989422804014327f

// ---------------- Phase 1: mean_dW[b][s] — fully parallel ----------------
__global__ __launch_bounds__(256)
void vasicek_phase1_meandw(float* __restrict__ ws) {
  const int tid = threadIdx.x;
  const int lane = tid & 63;
  const int wv = tid >> 6;
  const int wid = blockIdx.x * 4 + wv;          // 0 .. 64*2520-1
  const int b = wid / NSTEPS;
  const int s = wid - b * NSTEPS;

  uint32_t kA, kB;
  tf2x32(0u, 1u, 0u, (uint32_t)s, kA, kB);      // split(key(1))[s]

  float sum = 0.f;
#pragma unroll
  for (int i = 0; i < 4; ++i) {
    uint32_t cnt = (uint32_t)(b * NQ + lane + i * 64);
    uint32_t q0, q1;
    tf2x32(kA, kB, 0u, cnt, q0, q1);
    float dw = bits_to_normal(q0 ^ q1) * SQDT;
    sum += dw;
  }
  sum += __shfl_xor(sum, 32, 64); sum += __shfl_xor(sum, 16, 64);
  sum += __shfl_xor(sum, 8, 64);  sum += __shfl_xor(sum, 4, 64);
  sum += __shfl_xor(sum, 2, 64);  sum += __shfl_xor(sum, 1, 64);
  if (lane == 0) ws[b * NSTEPS + s] = sum * (1.0f / 256.0f);
}

// ---- B-fragment machinery, k-PERMUTED to match the packed h1 layout:
// h1 dword l = (h1[l], h1[l+64]) => B dword d of tile T (lane q,n) must hold
// W2 rows (16T+4q+d, 64+16T+4q+d) at column 16*(4*half+C)+n, f16x2 packed.
#define BDECL(T, C) u32x4 b_##T##_##C;
#define BINIT(T, C) { \
  const int col_ = 16 * (4 * half + (C)) + n; \
  const int r0_ = 16 * (T) + 4 * q; \
  b_##T##_##C = (u32x4){ \
    pack_f16x2(W2src[(r0_ + 0) * 128 + col_], W2src[(r0_ + 64) * 128 + col_]), \
    pack_f16x2(W2src[(r0_ + 1) * 128 + col_], W2src[(r0_ + 65) * 128 + col_]), \
    pack_f16x2(W2src[(r0_ + 2) * 128 + col_], W2src[(r0_ + 66) * 128 + col_]), \
    pack_f16x2(W2src[(r0_ + 3) * 128 + col_], W2src[(r0_ + 67) * 128 + col_])}; \
  asm volatile("" : "+a"(b_##T##_##C)); /* pin in AGPR quad */ \
}
#define MFMA1(ACC, AF, BF) \
  asm("v_mfma_f32_16x16x32_f16 %0, %1, %2, %0" : "+v"(ACC) : "v"(AF), "a"(BF));

// Interleaved MFMA row: both steps' accs, dep distance 8 per chain.
#define MROW(T) \
  MFMA1(accA0, afA##T, b_##T##_0) MFMA1(accA1, afA##T, b_##T##_1) \
  MFMA1(accA2, afA##T, b_##T##_2) MFMA1(accA3, afA##T, b_##T##_3) \
  MFMA1(accB0, afB##T, b_##T##_0) MFMA1(accB1, afB##T, b_##T##_1) \
  MFMA1(accB2, afB##T, b_##T##_2) MFMA1(accB3, afB##T, b_##T##_3)

// layer-1, SPLIT: this wave computes h1[jH] only (jH = 64*half+lane); writes
// f16 halves of the pair-shared packed dwords. Value dwords [0..63],
// tangent dwords [80..143] (+320B == 64 mod 128: bank-disjoint from value).
#define STAGE3S(TV, SLOT, ST, RANCH) { \
  float pre_ = __builtin_fmaf((TV), w11, __builtin_fmaf((RANCH), w10, c1)); \
  float e_ = eigen_erf_fast(pre_ * INV_SQRT2); \
  float cg_ = (e_ + 1.0f) * 0.5f; \
  float v_ = pre_ * cg_; \
  float ph_ = PHI_C * __expf(-0.5f * pre_ * pre_); \
  float d_ = __builtin_fmaf(pre_, ph_, cg_) * w10S; \
  ((uint16_t*)&h1x[SLOT][ST][mlp][0])[2 * lane + half] = f32_to_f16bits(v_); \
  ((uint16_t*)&h1x[SLOT][ST][mlp][80])[2 * lane + half] = f32_to_f16bits(d_); \
}

// 4-wide interleaved DPP reduce (all four partials; results land in lane 63)
#define DPP4(CTRL, MASK) { \
  pvA = dpp_add<CTRL, MASK>(pvA); ptA = dpp_add<CTRL, MASK>(ptA); \
  pvB = dpp_add<CTRL, MASK>(pvB); ptB = dpp_add<CTRL, MASK>(ptB); }

// ---------------- Phase 2: scan, 64 blocks x 256 ---------------------------
__global__
__attribute__((amdgpu_flat_work_group_size(256, 256)))
__attribute__((amdgpu_waves_per_eu(1, 1)))
void vasicek_phase2_scan(
    const float* __restrict__ X, const float* __restrict__ r_ult,
    const float* __restrict__ mats,
    const float* __restrict__ Wp, const float* __restrict__ bp,
    const float* __restrict__ ln_g, const float* __restrict__ ln_b,
    const float* __restrict__ muW1, const float* __restrict__ mub1,
    const float* __restrict__ muW2, const float* __restrict__ mub2,
    const float* __restrict__ muW3, const float* __restrict__ mub3,
    const float* __restrict__ siW1, const float* __restrict__ sib1,
    const float* __restrict__ siW2, const float* __restrict__ sib2,
    const float* __restrict__ siW3, const float* __restrict__ sib3,
    const float* __restrict__ ws, float* __restrict__ out) {
  // [slot][step-of-pair][mlp][160]: value dw 0..63, pad, tangent dw 80..143
  __shared__ __align__(16) uint32_t h1x[2][2][2][160];
  __shared__ __align__(16) float meanw[NSTEPS];
  __shared__ float part[256];
  __shared__ float mbuf[64];
  __shared__ float ctx_lds[192];
  __shared__ __align__(16) float msum[2][2][4][2];  // [slot][step][wave][{v,t}]

  const int t = threadIdx.x;
  const int b = blockIdx.x;
  const int lane = t & 63;
  const int wv = t >> 6;

  for (int i = t; i < NSTEPS; i += 256) meanw[i] = ws[b * NSTEPS + i];

  // ---- context aggregator (all 256 threads, one T-row each) ----
  float h[64];
  {
    float x0 = X[(b * NT + t) * 2 + 0];
    float x1 = X[(b * NT + t) * 2 + 1];
    float s = 0.f;
#pragma unroll
    for (int c = 0; c < 64; ++c) {
      float pre = __builtin_fmaf(x1, Wp[64 + c], x0 * Wp[c]) + bp[c];
      h[c] = eigen_tanh(pre);
      s += h[c];
    }
    float m = s * 0.015625f;
    float vs = 0.f;
#pragma unroll
    for (int c = 0; c < 64; ++c) { float d = h[c] - m; vs = __builtin_fmaf(d, d, vs); }
    float den = sqrtf(vs * 0.015625f + 1e-5f);
#pragma unroll
    for (int c = 0; c < 64; ++c)
      h[c] = ((h[c] - m) / den) * ln_g[c] + ln_b[c];
  }
#pragma unroll
  for (int c = 0; c < 64; ++c) {
    float v = h[c];
    v += __shfl_xor(v, 32, 64); v += __shfl_xor(v, 16, 64);
    v += __shfl_xor(v, 8, 64);  v += __shfl_xor(v, 4, 64);
    v += __shfl_xor(v, 2, 64);  v += __shfl_xor(v, 1, 64);
    if (lane == 0) part[wv * 64 + c] = v;
  }
  __syncthreads();
  if (t < 64) {
    float m = ((part[t] + part[64 + t]) + (part[128 + t] + part[192 + t])) * (1.0f / 256.0f);
    mbuf[t] = m;
    ctx_lds[t] = m;
  }
  __syncthreads();
#pragma unroll
  for (int c = 0; c < 64; ++c) {
    float d = h[c] - mbuf[c];
    float v = d * d;
    v += __shfl_xor(v, 32, 64); v += __shfl_xor(v, 16, 64);
    v += __shfl_xor(v, 8, 64);  v += __shfl_xor(v, 4, 64);
    v += __shfl_xor(v, 2, 64);  v += __shfl_xor(v, 1, 64);
    if (lane == 0) part[wv * 64 + c] = v;
  }
  if (t == 255) {
#pragma unroll
    for (int c = 0; c < 64; ++c) ctx_lds[128 + c] = h[c];
  }
  __syncthreads();
  if (t < 64) {
    float vs = (part[t] + part[64 + t]) + (part[128 + t] + part[192 + t]);
    ctx_lds[64 + t] = sqrtf(vs / 255.0f);
  }
  __syncthreads();

  // ---- per-wave roles: mlp = wv>>1 (0=mu,1=si), half = wv&1 ----
  const int mlp = wv >> 1;
  const int half = wv & 1;
  const int jH = 64 * half + lane;            // layer-1 ownership (SPLIT)
  const int jE = jH;                          // epilogue ownership (h2 half)
  const float* W1 = mlp == 0 ? muW1 : siW1;
  const float* W2src = mlp == 0 ? muW2 : siW2;
  float c1 = (mlp == 0 ? mub1 : sib1)[jH];
  for (int c = 0; c < 192; ++c) {
    const float cx = ctx_lds[c];
    c1 = __builtin_fmaf(cx, W1[(2 + c) * 128 + jH], c1);
  }
  const float w10 = W1[jH], w11 = W1[128 + jH];
  const float w10S = w10 * TSC;
  const float b2E = (mlp == 0 ? mub2 : sib2)[jE];
  const float w3E = (mlp == 0 ? muW3 : siW3)[jE];
  const float b3mu = mub3[0], b3si = sib3[0];

  const int q = lane >> 4, n = lane & 15;

  // this wave's 4 col-tiles of its W2 -> 16 AGPR quads (one-time; pinned)
  BDECL(0,0) BDECL(0,1) BDECL(0,2) BDECL(0,3)
  BDECL(1,0) BDECL(1,1) BDECL(1,2) BDECL(1,3)
  BDECL(2,0) BDECL(2,1) BDECL(2,2) BDECL(2,3)
  BDECL(3,0) BDECL(3,1) BDECL(3,2) BDECL(3,3)
  BINIT(0,0) BINIT(0,1) BINIT(0,2) BINIT(0,3)
  BINIT(1,0) BINIT(1,1) BINIT(1,2) BINIT(1,3)
  BINIT(2,0) BINIT(2,1) BINIT(2,2) BINIT(2,3)
  BINIT(3,0) BINIT(3,1) BINIT(3,2) BINIT(3,3)

  // A-row = lane&15; rows with (row&3)==1 read the tangent region (+80 dw).
  const bool tsel = (lane & 3) == 1;
  const int toff = tsel ? 80 : 0;

  float r = r_ult[b];
  float area = 0.f;
  float aA = r, aB = r;   // anchor queue (aA = anchor for this body's updates)

  // ---- prologue: layer-1 for steps 0,1 -> slot 0, anchor r0 ----
  STAGE3S(0.0f, 0, 0, r)
  STAGE3S(TSTEP, 0, 1, r)
  __syncthreads();

  // ---- main loop: body k handles updates {2k,2k+1}, STAGE1C for
  // {2k+2,2k+3} (h1 from slot oslot, body k-1), STAGE3 for {2k+4,2k+5}
  // (-> slot, anchor = r at body entry). One barrier per body. ----
#pragma unroll 1
  for (int k = -1; k < 1260; ++k) {
    const int slot = k & 1;
    const int oslot = slot ^ 1;

    // early-issue LDS reads (consumed ~200cy later)
    const float4 mA0 = *(const float4*)&msum[slot][0][0][0];  // mu: w0,w1 (v,t)
    const float4 mA1 = *(const float4*)&msum[slot][0][2][0];  // si: w2,w3
    const float4 mB0 = *(const float4*)&msum[slot][1][0][0];
    const float4 mB1 = *(const float4*)&msum[slot][1][2][0];
    const int mwi = k < 0 ? 0 : 2 * k;
    const float2 mw2 = *(const float2*)&meanw[mwi];

    const uint32_t* vb0 = &h1x[oslot][0][mlp][0];
    const uint32_t* vb1 = &h1x[oslot][1][mlp][0];
    const u32x4* hqA = (const u32x4*)(vb0 + toff);
    const u32x4* hqB = (const u32x4*)(vb1 + toff);
    u32x4 afA0 = hqA[q], afA1 = hqA[4 + q], afA2 = hqA[8 + q], afA3 = hqA[12 + q];
    u32x4 afB0 = hqB[q], afB1 = hqB[4 + q], afB2 = hqB[8 + q], afB3 = hqB[12 + q];

    // layer-1 for steps {2k+4, 2k+5} at anchor rE (entry r; independent of
    // this body's updates)
    const float rE = r;
    STAGE3S(TSTEP * (float)(2 * k + 4), slot, 0, rE)
    STAGE3S(TSTEP * (float)(2 * k + 5), slot, 1, rE)

    // serial updates for steps {2k, 2k+1}; both msums anchored at aA
    if (k >= 0) {
      float druA = (r - aA) * TSC_INV;
      float muA = __builtin_fmaf(mA0.y + mA0.w, druA, (mA0.x + mA0.z) + b3mu);
      float zA  = __builtin_fmaf(mA1.y + mA1.w, druA, (mA1.x + mA1.z) + b3si);
      float siA = softplus_fast(zA) + 1e-5f;
      r = __fadd_rn(__fadd_rn(r, __fmul_rn(muA, DTF)), __fmul_rn(siA, mw2.x));
      area = __fadd_rn(area, __fmul_rn(r, DTF));
      float druB = (r - aA) * TSC_INV;
      float muB = __builtin_fmaf(mB0.y + mB0.w, druB, (mB0.x + mB0.z) + b3mu);
      float zB  = __builtin_fmaf(mB1.y + mB1.w, druB, (mB1.x + mB1.z) + b3si);
      float siB = softplus_fast(zB) + 1e-5f;
      r = __fadd_rn(__fadd_rn(r, __fmul_rn(muB, DTF)), __fmul_rn(siB, mw2.y));
      area = __fadd_rn(area, __fmul_rn(r, DTF));
    }
    aA = aB;
    aB = rE;

    // layer-2/3 (value+tangent) for steps {2k+2, 2k+3} -> msum[oslot]
    f32x4 accA0 = {0,0,0,0}, accA1 = {0,0,0,0}, accA2 = {0,0,0,0}, accA3 = {0,0,0,0};
    f32x4 accB0 = {0,0,0,0}, accB1 = {0,0,0,0}, accB2 = {0,0,0,0}, accB3 = {0,0,0,0};
    MROW(0) MROW(1) MROW(2) MROW(3)
    asm volatile("s_nop 7\n\ts_nop 7"
                 : "+v"(accA0), "+v"(accA1), "+v"(accA2), "+v"(accA3),
                   "+v"(accB0), "+v"(accB1), "+v"(accB2), "+v"(accB3));

    float yvA = (q == 0 ? accA0[0] : q == 1 ? accA1[0] : q == 2 ? accA2[0] : accA3[0]) + b2E;
    float ytA = (q == 0 ? accA0[1] : q == 1 ? accA1[1] : q == 2 ? accA2[1] : accA3[1]);
    float yvB = (q == 0 ? accB0[0] : q == 1 ? accB1[0] : q == 2 ? accB2[0] : accB3[0]) + b2E;
    float ytB = (q == 0 ? accB0[1] : q == 1 ? accB1[1] : q == 2 ? accB2[1] : accB3[1]);

    float evA = eigen_erf_fast(yvA * INV_SQRT2);
    float cvA = (evA + 1.0f) * 0.5f;
    float pvA = yvA * cvA * w3E;
    float phA = PHI_C * __expf(-0.5f * yvA * yvA);
    float ptA = __builtin_fmaf(yvA, phA, cvA) * ytA * w3E;

    float evB = eigen_erf_fast(yvB * INV_SQRT2);
    float cvB = (evB + 1.0f) * 0.5f;
    float pvB = yvB * cvB * w3E;
    float phB = PHI_C * __expf(-0.5f * yvB * yvB);
    float ptB = __builtin_fmaf(yvB, phB, cvB) * ytB * w3E;

    DPP4(0x111, 0xf) DPP4(0x112, 0xf) DPP4(0x114, 0xf)
    DPP4(0x118, 0xf) DPP4(0x142, 0xa) DPP4(0x143, 0xc)

    if (lane == 63) {
      msum[oslot][0][wv][0] = pvA; msum[oslot][0][wv][1] = ptA;
      msum[oslot][1][wv][0] = pvB; msum[oslot][1][wv][1] = ptB;
    }
    __syncthreads();  // publish msum[oslot] + h1x[slot] (the ONLY barrier)
  }

  if (t < NMAT) {
    float mx = mats[0];
#pragma unroll
    for (int i = 1; i < NMAT; ++i) mx = fmaxf(mx, mats[i]);
    const float mm = mats[t];
    const float frac = mm / (mx + 1e-12f);
    out[b * NMAT + t] = (area * frac) / (mm + 1e-12f);
  }
}

extern "C" void kernel_launch(void* const* d_in, const int* in_sizes, int n_in,
                              void* d_out, int out_size, void* d_ws, size_t ws_size,
                              hipStream_t stream) {
  (void)in_sizes; (void)n_in; (void)ws_size; (void)out_size;
  const float* X      = (const float*)d_in[0];
  const float* r_ult  = (const float*)d_in[1];
  const float* mats   = (const float*)d_in[2];
  const float* Wp     = (const float*)d_in[3];
  const float* bp     = (const float*)d_in[4];
  const float* ln_g   = (const float*)d_in[5];
  const float* ln_b   = (const float*)d_in[6];
  const float* muW1   = (const float*)d_in[7];
  const float* mub1   = (const float*)d_in[8];
  const float* muW2   = (const float*)d_in[9];
  const float* mub2   = (const float*)d_in[10];
  const float* muW3   = (const float*)d_in[11];
  const float* mub3   = (const float*)d_in[12];
  const float* siW1   = (const float*)d_in[13];
  const float* sib1   = (const float*)d_in[14];
  const float* siW2   = (const float*)d_in[15];
  const float* sib2   = (const float*)d_in[16];
  const float* siW3   = (const float*)d_in[17];
  const float* sib3   = (const float*)d_in[18];
  float* ws = (float*)d_ws;   // 64*2520*4 = 645,120 bytes

  hipLaunchKernelGGL(vasicek_phase1_meandw,
                     dim3(NB * NSTEPS / 4), dim3(256), 0, stream, ws);
  hipLaunchKernelGGL(vasicek_phase2_scan,
                     dim3(NB), dim3(256), 0, stream,
                     X, r_ult, mats, Wp, bp, ln_g, ln_b,
                     muW1, mub1, muW2, mub2, muW3, mub3,
                     siW1, sib1, siW2, sib2, siW3, sib3,
                     ws, (float*)d_out);
}

// Round 4
// 932.905 us; speedup vs baseline: 2.0029x; 1.7279x over previous
//
#include <hip/hip_runtime.h>
#include <stdint.h>

// ModeloNeuralVasicek — two-phase mean-recursion.
// Round 20: 8-step MFMA batching. R19 post-mortem: per-CU LDS unit + per-wave
// VALU issue bound at ~2753cy/body(2 steps); 14/16 MFMA A-rows wasted.
// Now A-row n = (step n>>1, type n&1): one 16-MFMA group (4 col-chunks x
// K=128) computes layer-2 VAL+TANGENT for 8 steps. Per wave per 8 steps:
// 16 MFMA (was 128), 4 A-frag b128 reads (per-lane region-addressed,
// stride 272B == 16 mod 128 -> even bank spread), 1 barrier (was 4).
// Anchors upgraded to predicted trajectory: a_j = r + mu7*DT*(8+j) +
// si7*prefix(mw) (mw known from phase 1), so |r - a| ~ 1e-3 and the
// forward-mode tangent correction keeps linearization error ~1e-7.
// D rows: lane(q,n) acc[e] = (step 2q+(e>>1), type e&1) at col 64*half+16C+n.

#define NSTEPS 2520
#define NB 64
#define NT 256
#define NQ 256
#define NMAT 7
#define NBODY 315
#define MWPAD 2544

typedef uint32_t u32x4 __attribute__((ext_vector_type(4)));
typedef float f32x4 __attribute__((ext_vector_type(4)));

__device__ __forceinline__ uint32_t rotl32(uint32_t v, int n) {
  return (v << n) | (v >> (32 - n));
}

// Threefry-2x32, 20 rounds — matches jax._src.prng.threefry2x32 exactly.
__device__ __forceinline__ void tf2x32(uint32_t k0, uint32_t k1,
                                       uint32_t x0, uint32_t x1,
                                       uint32_t& o0, uint32_t& o1) {
  const uint32_t k2 = k0 ^ k1 ^ 0x1BD11BDAu;
  x0 += k0; x1 += k1;
#define R4(a,b,c,d) \
  x0 += x1; x1 = rotl32(x1,(a)); x1 ^= x0; \
  x0 += x1; x1 = rotl32(x1,(b)); x1 ^= x0; \
  x0 += x1; x1 = rotl32(x1,(c)); x1 ^= x0; \
  x0 += x1; x1 = rotl32(x1,(d)); x1 ^= x0;
  R4(13,15,26,6)  x0 += k1; x1 += k2 + 1u;
  R4(17,29,16,24) x0 += k2; x1 += k0 + 2u;
  R4(13,15,26,6)  x0 += k0; x1 += k1 + 3u;
  R4(17,29,16,24) x0 += k1; x1 += k2 + 4u;
  R4(13,15,26,6)  x0 += k2; x1 += k0 + 5u;
#undef R4
  o0 = x0; o1 = x1;
}

// fast reciprocal: v_rcp + one Newton step (~1e-7 rel; replaces full f32 div)
__device__ __forceinline__ float fast_rcp(float q) {
  float r = __builtin_amdgcn_rcpf(q);
  r = __builtin_fmaf(r, __builtin_fmaf(-q, r, 1.0f), r);
  return r;
}

// Eigen/XLA generic_fast_tanh_float (preamble only; keep full precision).
__device__ __forceinline__ float eigen_tanh(float a_x) {
  float x = fminf(fmaxf(a_x, -7.90531110763549805f), 7.90531110763549805f);
  float x2 = x * x;
  float p = __builtin_fmaf(x2, -2.76076847742355e-16f, 2.00018790482477e-13f);
  p = __builtin_fmaf(x2, p, -8.60467152213735e-11f);
  p = __builtin_fmaf(x2, p, 5.12229709037114e-08f);
  p = __builtin_fmaf(x2, p, 1.48572235717979e-05f);
  p = __builtin_fmaf(x2, p, 6.37261928875436e-04f);
  p = __builtin_fmaf(x2, p, 4.89352455891786e-03f);
  p = x * p;
  float q = __builtin_fmaf(x2, 1.19825839466702e-06f, 1.18534705686654e-04f);
  q = __builtin_fmaf(x2, q, 2.26843463243900e-03f);
  q = __builtin_fmaf(x2, q, 4.89352518554385e-03f);
  float rr = p / q;
  return (fabsf(a_x) < 0.0004f) ? a_x : rr;
}

// Eigen/XLA erf polynomial with rcp-division (scan loop hot path).
__device__ __forceinline__ float eigen_erf_fast(float a_x) {
  float x = fminf(fmaxf(a_x, -4.0f), 4.0f);
  float x2 = x * x;
  float p = __builtin_fmaf(x2, -2.72614225801306e-10f, 2.77068142495902e-08f);
  p = __builtin_fmaf(x2, p, -2.10102402082508e-06f);
  p = __builtin_fmaf(x2, p, -5.69250639462346e-05f);
  p = __builtin_fmaf(x2, p, -7.34990630326855e-04f);
  p = __builtin_fmaf(x2, p, -2.95459980854025e-03f);
  p = __builtin_fmaf(x2, p, -1.60960333262415e-02f);
  p = x * p;
  float q = __builtin_fmaf(x2, -1.45660718464996e-05f, -2.13374055278905e-04f);
  q = __builtin_fmaf(x2, q, -1.68282697438203e-03f);
  q = __builtin_fmaf(x2, q, -7.37332916720468e-03f);
  q = __builtin_fmaf(x2, q, -1.42647390514189e-02f);
  return p * fast_rcp(q);
}

// fast softplus: __expf/__logf (v_exp/v_log based), abs err ~1e-6
__device__ __forceinline__ float softplus_fast(float x) {
  float e = __expf(-fabsf(x));
  return fmaxf(x, 0.0f) + __logf(1.0f + e);
}

// XLA chlo.erf_inv f32 (Giles polynomial) — phase 1 only, keep exact.
__device__ __forceinline__ float erfinv_xla(float x) {
  float w = -logf((1.0f - x) * (1.0f + x));
  float p;
  if (w < 5.0f) {
    w = w - 2.5f;
    p = 2.81022636e-08f;
    p = __builtin_fmaf(p, w, 3.43273939e-07f);
    p = __builtin_fmaf(p, w, -3.5233877e-06f);
    p = __builtin_fmaf(p, w, -4.39150654e-06f);
    p = __builtin_fmaf(p, w, 0.00021858087f);
    p = __builtin_fmaf(p, w, -0.00125372503f);
    p = __builtin_fmaf(p, w, -0.00417768164f);
    p = __builtin_fmaf(p, w, 0.246640727f);
    p = __builtin_fmaf(p, w, 1.50140941f);
  } else {
    w = sqrtf(w) - 3.0f;
    p = -0.000200214257f;
    p = __builtin_fmaf(p, w, 0.000100950558f);
    p = __builtin_fmaf(p, w, 0.00134934322f);
    p = __builtin_fmaf(p, w, -0.00367342844f);
    p = __builtin_fmaf(p, w, 0.00573950773f);
    p = __builtin_fmaf(p, w, -0.0076224613f);
    p = __builtin_fmaf(p, w, 0.00943887047f);
    p = __builtin_fmaf(p, w, 1.00167406f);
    p = __builtin_fmaf(p, w, 2.83297682f);
  }
  return p * x;
}

__device__ __forceinline__ float bits_to_normal(uint32_t bits) {
  const float MINVAL = -0.999999940395355224609375f;
  uint32_t fb = (bits >> 9) | 0x3F800000u;
  float f01 = __uint_as_float(fb) - 1.0f;
  float u = f01 * 2.0f + MINVAL;
  u = fmaxf(u, MINVAL);
  return 1.41421356237309515f * erfinv_xla(u);
}

__device__ __forceinline__ uint16_t f32_to_f16bits(float x) {
  _Float16 hv = (_Float16)x;  // RNE
  return __builtin_bit_cast(uint16_t, hv);
}

__device__ __forceinline__ uint32_t pack_f16x2(float lo, float hi) {
  return (uint32_t)f32_to_f16bits(lo) | ((uint32_t)f32_to_f16bits(hi) << 16);
}

// DPP add: v += dpp_move(v) — VALU pipe. 0x111..0x118 = row_shr 1..8.
template <int CTRL, int RMASK>
__device__ __forceinline__ float dpp_add(float v) {
  int x = __builtin_amdgcn_update_dpp(0, __float_as_int(v), CTRL, RMASK, 0xf, true);
  return v + __int_as_float(x);
}

#define DTF  0.00396825396825396826f
#define SQDT 0.06299407883487120442f
#define TSTEP (1.0f / 2519.0f)
// tangents scaled by 64 for f16 headroom; update folds the 1/64 back in
#define TSC      64.0f
#define TSC_INV  0.015625f
#define INV_SQRT2 0.7071067811865475f
#define PHI_C     0.3989422804014327f

// ---------------- Phase 1: mean_dW[b][s] — fully parallel ----------------
__global__ __launch_bounds__(256)
void vasicek_phase1_meandw(float* __restrict__ ws) {
  const int tid = threadIdx.x;
  const int lane = tid & 63;
  const int wv = tid >> 6;
  const int wid = blockIdx.x * 4 + wv;          // 0 .. 64*2520-1
  const int b = wid / NSTEPS;
  const int s = wid - b * NSTEPS;

  uint32_t kA, kB;
  tf2x32(0u, 1u, 0u, (uint32_t)s, kA, kB);      // split(key(1))[s]

  float sum = 0.f;
#pragma unroll
  for (int i = 0; i < 4; ++i) {
    uint32_t cnt = (uint32_t)(b * NQ + lane + i * 64);
    uint32_t q0, q1;
    tf2x32(kA, kB, 0u, cnt, q0, q1);
    float dw = bits_to_normal(q0 ^ q1) * SQDT;
    sum += dw;
  }
  sum += __shfl_xor(sum, 32, 64); sum += __shfl_xor(sum, 16, 64);
  sum += __shfl_xor(sum, 8, 64);  sum += __shfl_xor(sum, 4, 64);
  sum += __shfl_xor(sum, 2, 64);  sum += __shfl_xor(sum, 1, 64);
  if (lane == 0) ws[b * NSTEPS + s] = sum * (1.0f / 256.0f);
}

// ---- B-fragment machinery, k-PERMUTED (unchanged from R17/R19):
// B dword d of K-chunk T (lane q,n) holds W2 rows (16T+4q+d, 64+16T+4q+d)
// at column 64*half + 16*C + n, f16x2 packed.
#define BDECL(T, C) u32x4 b_##T##_##C;
#define BINIT(T, C) { \
  const int col_ = 16 * (4 * half + (C)) + n; \
  const int r0_ = 16 * (T) + 4 * q; \
  b_##T##_##C = (u32x4){ \
    pack_f16x2(W2src[(r0_ + 0) * 128 + col_], W2src[(r0_ + 64) * 128 + col_]), \
    pack_f16x2(W2src[(r0_ + 1) * 128 + col_], W2src[(r0_ + 65) * 128 + col_]), \
    pack_f16x2(W2src[(r0_ + 2) * 128 + col_], W2src[(r0_ + 66) * 128 + col_]), \
    pack_f16x2(W2src[(r0_ + 3) * 128 + col_], W2src[(r0_ + 67) * 128 + col_])}; \
  asm volatile("" : "+a"(b_##T##_##C)); /* pin in AGPR quad */ \
}
#define MFMA1(ACC, AF, BF) \
  asm("v_mfma_f32_16x16x32_f16 %0, %1, %2, %0" : "+v"(ACC) : "v"(AF), "a"(BF));

// layer-1 for step (J of batch), time TV, anchor RANCH; writes f16 halves of
// regions 2J (value) and 2J+1 (tangent*64) for this wave's jH element.
#define STAGE3S(TV, SLOT, J, RANCH) { \
  float pre_ = __builtin_fmaf((TV), w11, __builtin_fmaf((RANCH), w10, c1)); \
  float e_ = eigen_erf_fast(pre_ * INV_SQRT2); \
  float cg_ = (e_ + 1.0f) * 0.5f; \
  float v_ = pre_ * cg_; \
  float ph_ = PHI_C * __expf(-0.5f * pre_ * pre_); \
  float d_ = __builtin_fmaf(pre_, ph_, cg_) * w10S; \
  ((uint16_t*)&h1x[SLOT][mlp][2*(J)][0])[2 * lane + half] = f32_to_f16bits(v_); \
  ((uint16_t*)&h1x[SLOT][mlp][2*(J)+1][0])[2 * lane + half] = f32_to_f16bits(d_); \
}

// epilogue for one col-chunk: acc elems e = (step 2q+(e>>1), type e&1)
#define EPI(AC, BC, WC) { \
  float yv0 = AC[0] + (BC); float yt0 = AC[1]; \
  float yv1 = AC[2] + (BC); float yt1 = AC[3]; \
  float e0 = eigen_erf_fast(yv0 * INV_SQRT2); float c0_ = (e0 + 1.0f) * 0.5f; \
  float e1 = eigen_erf_fast(yv1 * INV_SQRT2); float c1_ = (e1 + 1.0f) * 0.5f; \
  pv0 = __builtin_fmaf((WC) * yv0, c0_, pv0); \
  pv1 = __builtin_fmaf((WC) * yv1, c1_, pv1); \
  float p0_ = PHI_C * __expf(-0.5f * yv0 * yv0); \
  float p1_ = PHI_C * __expf(-0.5f * yv1 * yv1); \
  float g0_ = __builtin_fmaf(yv0, p0_, c0_); \
  float g1_ = __builtin_fmaf(yv1, p1_, c1_); \
  pt0 = __builtin_fmaf((WC) * g0_, yt0, pt0); \
  pt1 = __builtin_fmaf((WC) * g1_, yt1, pt1); \
}

#define DPPROW(CTRL) { \
  pv0 = dpp_add<CTRL, 0xf>(pv0); pt0 = dpp_add<CTRL, 0xf>(pt0); \
  pv1 = dpp_add<CTRL, 0xf>(pv1); pt1 = dpp_add<CTRL, 0xf>(pt1); }

// ---------------- Phase 2: scan, 64 blocks x 256 ---------------------------
__global__
__attribute__((amdgpu_flat_work_group_size(256, 256)))
__attribute__((amdgpu_waves_per_eu(1, 1)))
void vasicek_phase2_scan(
    const float* __restrict__ X, const float* __restrict__ r_ult,
    const float* __restrict__ mats,
    const float* __restrict__ Wp, const float* __restrict__ bp,
    const float* __restrict__ ln_g, const float* __restrict__ ln_b,
    const float* __restrict__ muW1, const float* __restrict__ mub1,
    const float* __restrict__ muW2, const float* __restrict__ mub2,
    const float* __restrict__ muW3, const float* __restrict__ mub3,
    const float* __restrict__ siW1, const float* __restrict__ sib1,
    const float* __restrict__ siW2, const float* __restrict__ sib2,
    const float* __restrict__ siW3, const float* __restrict__ sib3,
    const float* __restrict__ ws, float* __restrict__ out) {
  // [slot][mlp][region n = 2*step+type][68 dw] (region stride 272B == 16 mod 128)
  __shared__ __align__(16) uint32_t h1x[2][2][16][68];
  __shared__ __align__(16) float meanw[MWPAD];
  __shared__ float part[256];
  __shared__ float mbuf[64];
  __shared__ float ctx_lds[192];
  __shared__ __align__(16) float msum[2][4][4][4];  // [slot][wave][q][pv0,pt0,pv1,pt1]

  const int t = threadIdx.x;
  const int b = blockIdx.x;
  const int lane = t & 63;
  const int wv = t >> 6;

  for (int i = t; i < MWPAD; i += 256)
    meanw[i] = i < NSTEPS ? ws[b * NSTEPS + i] : 0.f;

  // ---- context aggregator (all 256 threads, one T-row each) ----
  float h[64];
  {
    float x0 = X[(b * NT + t) * 2 + 0];
    float x1 = X[(b * NT + t) * 2 + 1];
    float s = 0.f;
#pragma unroll
    for (int c = 0; c < 64; ++c) {
      float pre = __builtin_fmaf(x1, Wp[64 + c], x0 * Wp[c]) + bp[c];
      h[c] = eigen_tanh(pre);
      s += h[c];
    }
    float m = s * 0.015625f;
    float vs = 0.f;
#pragma unroll
    for (int c = 0; c < 64; ++c) { float d = h[c] - m; vs = __builtin_fmaf(d, d, vs); }
    float den = sqrtf(vs * 0.015625f + 1e-5f);
#pragma unroll
    for (int c = 0; c < 64; ++c)
      h[c] = ((h[c] - m) / den) * ln_g[c] + ln_b[c];
  }
#pragma unroll
  for (int c = 0; c < 64; ++c) {
    float v = h[c];
    v += __shfl_xor(v, 32, 64); v += __shfl_xor(v, 16, 64);
    v += __shfl_xor(v, 8, 64);  v += __shfl_xor(v, 4, 64);
    v += __shfl_xor(v, 2, 64);  v += __shfl_xor(v, 1, 64);
    if (lane == 0) part[wv * 64 + c] = v;
  }
  __syncthreads();
  if (t < 64) {
    float m = ((part[t] + part[64 + t]) + (part[128 + t] + part[192 + t])) * (1.0f / 256.0f);
    mbuf[t] = m;
    ctx_lds[t] = m;
  }
  __syncthreads();
#pragma unroll
  for (int c = 0; c < 64; ++c) {
    float d = h[c] - mbuf[c];
    float v = d * d;
    v += __shfl_xor(v, 32, 64); v += __shfl_xor(v, 16, 64);
    v += __shfl_xor(v, 8, 64);  v += __shfl_xor(v, 4, 64);
    v += __shfl_xor(v, 2, 64);  v += __shfl_xor(v, 1, 64);
    if (lane == 0) part[wv * 64 + c] = v;
  }
  if (t == 255) {
#pragma unroll
    for (int c = 0; c < 64; ++c) ctx_lds[128 + c] = h[c];
  }
  __syncthreads();
  if (t < 64) {
    float vs = (part[t] + part[64 + t]) + (part[128 + t] + part[192 + t]);
    ctx_lds[64 + t] = sqrtf(vs / 255.0f);
  }
  __syncthreads();

  // ---- per-wave roles: mlp = wv>>1 (0=mu,1=si), half = wv&1 ----
  const int mlp = wv >> 1;
  const int half = wv & 1;
  const int jH = 64 * half + lane;            // layer-1 ownership
  const float* W1 = mlp == 0 ? muW1 : siW1;
  const float* W2src = mlp == 0 ? muW2 : siW2;
  float c1 = (mlp == 0 ? mub1 : sib1)[jH];
  for (int c = 0; c < 192; ++c) {
    const float cx = ctx_lds[c];
    c1 = __builtin_fmaf(cx, W1[(2 + c) * 128 + jH], c1);
  }
  const float w10 = W1[jH], w11 = W1[128 + jH];
  const float w10S = w10 * TSC;
  const float b3mu = mub3[0], b3si = sib3[0];

  const int q = lane >> 4, n = lane & 15;

  // per-lane epilogue constants for its 4 col-chunks (col = 64*half+16C+n)
  const float* b2p = mlp == 0 ? mub2 : sib2;
  const float* w3p = mlp == 0 ? muW3 : siW3;
  const int colb = 64 * half + n;
  const float b2C0 = b2p[colb],      w3C0 = w3p[colb];
  const float b2C1 = b2p[colb + 16], w3C1 = w3p[colb + 16];
  const float b2C2 = b2p[colb + 32], w3C2 = w3p[colb + 32];
  const float b2C3 = b2p[colb + 48], w3C3 = w3p[colb + 48];

  // this wave's 4 col-tiles of its W2 -> 16 AGPR quads (one-time; pinned)
  BDECL(0,0) BDECL(0,1) BDECL(0,2) BDECL(0,3)
  BDECL(1,0) BDECL(1,1) BDECL(1,2) BDECL(1,3)
  BDECL(2,0) BDECL(2,1) BDECL(2,2) BDECL(2,3)
  BDECL(3,0) BDECL(3,1) BDECL(3,2) BDECL(3,3)
  BINIT(0,0) BINIT(0,1) BINIT(0,2) BINIT(0,3)
  BINIT(1,0) BINIT(1,1) BINIT(1,2) BINIT(1,3)
  BINIT(2,0) BINIT(2,1) BINIT(2,2) BINIT(2,3)
  BINIT(3,0) BINIT(3,1) BINIT(3,2) BINIT(3,3)

  // A-frag base pointers: region n of this wave's MLP, quad offset q.
  // region stride 68 dw = 17 u32x4; af_T at +4T quads.
  const u32x4* hq0 = ((const u32x4*)&h1x[0][mlp][0][0]) + 17 * n + q;
  const u32x4* hq1 = ((const u32x4*)&h1x[1][mlp][0][0]) + 17 * n + q;

  float r = r_ult[b];
  float area = 0.f;
  float aA[8], aB[8];
  float mu_c = 0.f, si_c = 0.f;

  // ---- prologue: layer-1 for batch 0 (steps 0..7), anchor r0 -> slot 0 ----
#pragma unroll
  for (int j = 0; j < 8; ++j) {
    aB[j] = r;
    const float tv0 = TSTEP * (float)j;
    STAGE3S(tv0, 0, j, r)
  }
#pragma unroll
  for (int j = 0; j < 8; ++j) aA[j] = r;   // placeholder (k=-1 updates skipped)
  __syncthreads();

  // ---- main loop: body k: updates batch k, MFMA batch k+1, STAGE3 batch k+2
#pragma unroll 1
  for (int k = -1; k < NBODY; ++k) {
    const int sl = k & 1;        // msum slot (batch k); h1 write slot (batch k+2)
    const int so = sl ^ 1;       // h1 read slot (batch k+1); msum write slot

    // early-issue LDS reads
    f32x4 mqs[4][4];
#pragma unroll
    for (int w = 0; w < 4; ++w)
#pragma unroll
      for (int qq = 0; qq < 4; ++qq)
        mqs[w][qq] = *(const f32x4*)&msum[sl][w][qq][0];

    const u32x4* hq = so ? hq1 : hq0;
    u32x4 af0 = hq[0], af1 = hq[4], af2 = hq[8], af3 = hq[12];

    const int u0 = k < 0 ? 0 : 8 * k;
    f32x4 mwa = *(const f32x4*)&meanw[u0];
    f32x4 mwb = *(const f32x4*)&meanw[u0 + 4];
    f32x4 mp0 = *(const f32x4*)&meanw[u0 + 8];
    f32x4 mp1 = *(const f32x4*)&meanw[u0 + 12];
    f32x4 mp2 = *(const f32x4*)&meanw[u0 + 16];
    f32x4 mp3 = *(const f32x4*)&meanw[u0 + 20];

    // MFMA batch k+1 (matrix pipe; overlaps the VALU work below)
    f32x4 ac0 = {0,0,0,0}, ac1 = {0,0,0,0}, ac2 = {0,0,0,0}, ac3 = {0,0,0,0};
    MFMA1(ac0, af0, b_0_0) MFMA1(ac1, af0, b_0_1) MFMA1(ac2, af0, b_0_2) MFMA1(ac3, af0, b_0_3)
    MFMA1(ac0, af1, b_1_0) MFMA1(ac1, af1, b_1_1) MFMA1(ac2, af1, b_1_2) MFMA1(ac3, af1, b_1_3)
    MFMA1(ac0, af2, b_2_0) MFMA1(ac1, af2, b_2_1) MFMA1(ac2, af2, b_2_2) MFMA1(ac3, af2, b_2_3)
    MFMA1(ac0, af3, b_3_0) MFMA1(ac1, af3, b_3_1) MFMA1(ac2, af3, b_3_2) MFMA1(ac3, af3, b_3_3)

    // serial updates for batch k (steps 8k..8k+7), anchors aA[j]
    if (k >= 0) {
      const float mwU[8] = {mwa[0], mwa[1], mwa[2], mwa[3],
                            mwb[0], mwb[1], mwb[2], mwb[3]};
#pragma unroll
      for (int j = 0; j < 8; ++j) {
        const int jr = j >> 1, je = 2 * (j & 1);
        float muv = mqs[0][jr][je]     + mqs[1][jr][je];
        float mut = mqs[0][jr][je + 1] + mqs[1][jr][je + 1];
        float siv = mqs[2][jr][je]     + mqs[3][jr][je];
        float sit = mqs[2][jr][je + 1] + mqs[3][jr][je + 1];
        float dru = (r - aA[j]) * TSC_INV;
        float mu = __builtin_fmaf(mut, dru, muv + b3mu);
        float z  = __builtin_fmaf(sit, dru, siv + b3si);
        float si = softplus_fast(z) + 1e-5f;
        r = __fadd_rn(__fadd_rn(r, __fmul_rn(mu, DTF)), __fmul_rn(si, mwU[j]));
        area = __fadd_rn(area, __fmul_rn(r, DTF));
        if (j == 7) { mu_c = mu; si_c = si; }
      }
    }
#pragma unroll
    for (int j = 0; j < 8; ++j) aA[j] = aB[j];

    // STAGE3 batch k+2 (steps 8k+16..8k+23) at predicted anchors
    {
      const float rE = r;
      const float mwP[16] = {mp0[0], mp0[1], mp0[2], mp0[3],
                             mp1[0], mp1[1], mp1[2], mp1[3],
                             mp2[0], mp2[1], mp2[2], mp2[3],
                             mp3[0], mp3[1], mp3[2], mp3[3]};
      float S = ((mwP[0] + mwP[1]) + (mwP[2] + mwP[3])) +
                ((mwP[4] + mwP[5]) + (mwP[6] + mwP[7]));
#pragma unroll
      for (int j = 0; j < 8; ++j) {
        if (j > 0) S += mwP[7 + j];
        float aj = __builtin_fmaf(mu_c, DTF * (float)(8 + j), rE);
        aj = __builtin_fmaf(si_c, S, aj);
        aB[j] = aj;
        const float tv = TSTEP * (float)(8 * k + 16 + j);
        STAGE3S(tv, sl, j, aj)
      }
    }

    // MFMA dst -> VALU read hazard fence
    asm volatile("s_nop 7\n\ts_nop 7"
                 : "+v"(ac0), "+v"(ac1), "+v"(ac2), "+v"(ac3));

    // epilogue batch k+1: gelu2 val+tan, per-row (16-lane) DPP reduce
    float pv0 = 0.f, pt0 = 0.f, pv1 = 0.f, pt1 = 0.f;
    EPI(ac0, b2C0, w3C0) EPI(ac1, b2C1, w3C1)
    EPI(ac2, b2C2, w3C2) EPI(ac3, b2C3, w3C3)
    DPPROW(0x111) DPPROW(0x112) DPPROW(0x114) DPPROW(0x118)
    if (n == 15) {
      *(f32x4*)&msum[so][wv][q][0] = (f32x4){pv0, pt0, pv1, pt1};
    }
    __syncthreads();  // publish msum[so] (batch k+1) + h1x[sl] (batch k+2)
  }

  if (t < NMAT) {
    float mx = mats[0];
#pragma unroll
    for (int i = 1; i < NMAT; ++i) mx = fmaxf(mx, mats[i]);
    const float mm = mats[t];
    const float frac = mm / (mx + 1e-12f);
    out[b * NMAT + t] = (area * frac) / (mm + 1e-12f);
  }
}

extern "C" void kernel_launch(void* const* d_in, const int* in_sizes, int n_in,
                              void* d_out, int out_size, void* d_ws, size_t ws_size,
                              hipStream_t stream) {
  (void)in_sizes; (void)n_in; (void)ws_size; (void)out_size;
  const float* X      = (const float*)d_in[0];
  const float* r_ult  = (const float*)d_in[1];
  const float* mats   = (const float*)d_in[2];
  const float* Wp     = (const float*)d_in[3];
  const float* bp     = (const float*)d_in[4];
  const float* ln_g   = (const float*)d_in[5];
  const float* ln_b   = (const float*)d_in[6];
  const float* muW1   = (const float*)d_in[7];
  const float* mub1   = (const float*)d_in[8];
  const float* muW2   = (const float*)d_in[9];
  const float* mub2   = (const float*)d_in[10];
  const float* muW3   = (const float*)d_in[11];
  const float* mub3   = (const float*)d_in[12];
  const float* siW1   = (const float*)d_in[13];
  const float* sib1   = (const float*)d_in[14];
  const float* siW2   = (const float*)d_in[15];
  const float* sib2   = (const float*)d_in[16];
  const float* siW3   = (const float*)d_in[17];
  const float* sib3   = (const float*)d_in[18];
  float* ws = (float*)d_ws;   // 64*2520*4 = 645,120 bytes

  hipLaunchKernelGGL(vasicek_phase1_meandw,
                     dim3(NB * NSTEPS / 4), dim3(256), 0, stream, ws);
  hipLaunchKernelGGL(vasicek_phase2_scan,
                     dim3(NB), dim3(256), 0, stream,
                     X, r_ult, mats, Wp, bp, ln_g, ln_b,
                     muW1, mub1, muW2, mub2, muW3, mub3,
                     siW1, sib1, siW2, sib2, siW3, sib3,
                     ws, (float*)d_out);
}